// Round 8
// baseline (690.832 us; speedup 1.0000x reference)
//
#include <hip/hip_runtime.h>
#include <stdint.h>

#define TT 512
#define BB 1024
#define NN 64

typedef __attribute__((ext_vector_type(8))) short short8;
typedef __attribute__((ext_vector_type(4))) float f32x4;

union W8 { uint32_t w[4]; short8 v; };

__device__ __forceinline__ uint32_t cvt_pk_bf16(float lo, float hi){
    uint32_t r;
    asm("v_cvt_pk_bf16_f32 %0, %1, %2" : "=v"(r) : "v"(lo), "v"(hi));
    return r;
}
// gfx950 cross-lane 16/32-group swaps (VALU, no LDS) — HW-validated R4.
__device__ __forceinline__ void perm32swap(uint32_t &a, uint32_t &b){
    asm("v_permlane32_swap_b32 %0, %1" : "+v"(a), "+v"(b));
}
__device__ __forceinline__ void perm16swap(uint32_t &a, uint32_t &b){
    asm("v_permlane16_swap_b32 %0, %1" : "+v"(a), "+v"(b));
}

// Detect input integer widths (harness may canonicalize int64->int32, bool->int32).
__global__ void __launch_bounds__(64, 1)
detect_kernel(const uint32_t* __restrict__ tgt, const uint8_t* __restrict__ msk,
              int* __restrict__ flags) {
    if (threadIdx.x == 0) {
        uint32_t s = 0;
        for (int i = 0; i < 128; ++i) s |= tgt[2 * i + 1];
        flags[0] = (s == 0) ? 1 : 0;   // 1 => target is int64
        uint32_t mz = 0;
        for (int i = 0; i < 8; ++i) mz |= msk[4*i+1] | msk[4*i+2] | msk[4*i+3];
        flags[1] = (mz == 0) ? 1 : 0;  // 1 => mask is int32
    }
}

// Gold-path score: fully parallel over (t, b). (Unchanged — passed R1-R7.)
__global__ void __launch_bounds__(256)
score_kernel(const float* __restrict__ emit, const float* __restrict__ trans,
             const float* __restrict__ strans, const float* __restrict__ etrans,
             const void* __restrict__ target, const void* __restrict__ mask,
             const int* __restrict__ flags, float* __restrict__ out)
{
    const int idx = blockIdx.x * 256 + threadIdx.x;   // T*B threads
    const int t = idx >> 10, b = idx & (BB - 1);
    const int t64 = flags[0], m32 = flags[1];

    auto getm = [&](int tt) -> int {
        if (m32) return ((const int*)mask)[(size_t)tt * BB + b] != 0;
        else     return ((const uint8_t*)mask)[(size_t)tt * BB + b] != 0;
    };
    auto gett = [&](int tt) -> int {
        if (t64) return (int)((const long long*)target)[(size_t)tt * BB + b];
        else     return ((const int*)target)[(size_t)tt * BB + b];
    };

    const int m  = getm(t);
    const int tg = gett(t);
    float term = 0.f;
    if (m)      term += emit[((size_t)t * BB + b) * NN + tg];
    if (t == 0) term += strans[tg];
    if (t > 0 && m) term += trans[gett(t - 1) * NN + tg];
    const int mn = (t == TT - 1) ? 0 : getm(t + 1);
    if (m && !mn) term += etrans[tg];   // t == len-1 (contiguous prefix)

    #pragma unroll
    for (int off = 1; off < 64; off <<= 1) term += __shfl_xor(term, off);
    __shared__ float sred[4];
    const int wid = threadIdx.x >> 6, lane = threadIdx.x & 63;
    if (lane == 0) sred[wid] = term;
    __syncthreads();
    if (threadIdx.x == 0)
        atomicAdd(out, -(sred[0] + sred[1] + sred[2] + sred[3]) * (1.0f / (float)BB));
}

// Forward scan, single wave per 16 chains (R4/R7-verified math) + SAME-WAVE
// LDS staging ring: 16 slots x 4KB. load(t+12) -> 3-step reg hold ->
// ds_write(t+9, swizzled) -> ds_read(t+1) prefetch -> compute(t).
// Load->write distance ~1000cyc covers HBM; no cross-wave sync anywhere.
__global__ void __launch_bounds__(64, 1)
crf_scan(const float* __restrict__ emit, const float* __restrict__ trans,
         const float* __restrict__ strans, const float* __restrict__ etrans,
         const void* __restrict__ mask, const int* __restrict__ flags,
         float* __restrict__ out)
{
    __shared__ float s_eb[16 * 1024];   // 64 KB ring

    const int lane = threadIdx.x & 63;
    const int q = lane >> 4;
    const int c = lane & 15;
    const int b0 = blockIdx.x << 4;
    const int b = b0 + c;
    const int m32 = flags[1];

    // ---- per-chain length (contiguous-prefix mask), q-lanes split T ----
    int lp = 0;
    if (m32) {
        const int* mp = (const int*)mask;
        #pragma unroll 8
        for (int i = 0; i < 128; ++i)
            lp += (mp[(size_t)(q * 128 + i) * BB + b] != 0) ? 1 : 0;
    } else {
        const uint8_t* mp = (const uint8_t*)mask;
        #pragma unroll 8
        for (int i = 0; i < 128; ++i)
            lp += (mp[(size_t)(q * 128 + i) * BB + b] != 0) ? 1 : 0;
    }
    lp += __shfl_xor(lp, 16);
    lp += __shfl_xor(lp, 32);
    const int len = lp;
    int maxlen = len;
    #pragma unroll
    for (int off = 1; off < 64; off <<= 1)
        maxlen = max(maxlen, __shfl_xor(maxlen, off));
    const int NSTEP = maxlen - 1;

    // ---- A-operand: E^T tiles, E[j][n]=exp(trans[j][n]) (HW-verified R3/R4) ----
    short8 Ef[4][2];
    #pragma unroll
    for (int mt = 0; mt < 4; ++mt) {
        #pragma unroll
        for (int kt = 0; kt < 2; ++kt) {
            W8 u;
            #pragma unroll
            for (int jj = 0; jj < 8; jj += 2) {
                float f0 = __expf(trans[(size_t)(32*kt + 8*q + jj    ) * NN + 16*mt + c]);
                float f1 = __expf(trans[(size_t)(32*kt + 8*q + jj + 1) * NN + 16*mt + c]);
                u.w[jj >> 1] = cvt_pk_bf16(f0, f1);
            }
            Ef[mt][kt] = u.v;
        }
    }
    float ee[4][4];
    #pragma unroll
    for (int mt = 0; mt < 4; ++mt)
        #pragma unroll
        for (int r = 0; r < 4; ++r)
            ee[mt][r] = __expf(etrans[16*mt + 4*q + r]);

    // ---- state init: S = exp(strans + emit[0]) ----
    f32x4 S[4];
    float m = 0.f, lz = 0.f;
    #pragma unroll
    for (int mt = 0; mt < 4; ++mt) {
        f32x4 e0 = *(const f32x4*)(emit + (size_t)b * NN + 16*mt + 4*q);
        #pragma unroll
        for (int r = 0; r < 4; ++r)
            S[mt][r] = __expf(strans[16*mt + 4*q + r] + e0[r]);
    }

    auto renorm = [&]() {   // exact per-chain power-of-2 rescale
        float x0 = fmaxf(fmaxf(S[0][0], S[0][1]), fmaxf(S[0][2], S[0][3]));
        float x1 = fmaxf(fmaxf(S[1][0], S[1][1]), fmaxf(S[1][2], S[1][3]));
        float x2 = fmaxf(fmaxf(S[2][0], S[2][1]), fmaxf(S[2][2], S[2][3]));
        float x3 = fmaxf(fmaxf(S[3][0], S[3][1]), fmaxf(S[3][2], S[3][3]));
        float mx = fmaxf(fmaxf(x0, x1), fmaxf(x2, x3));
        mx = fmaxf(mx, __shfl_xor(mx, 16));
        mx = fmaxf(mx, __shfl_xor(mx, 32));
        int ex = (int)((__float_as_uint(mx) >> 23) & 0xffu) - 127;
        float sc = __uint_as_float((uint32_t)(127 - ex) << 23);   // exact 2^-ex
        #pragma unroll
        for (int mt = 0; mt < 4; ++mt)
            #pragma unroll
            for (int r = 0; r < 4; ++r)
                S[mt][r] *= sc;
        m += (float)ex * 0.6931471805599453f;
    };
    renorm();

    auto extract_if = [&](int t) {   // latch logZ for chains with len == t
        if (__any(len == t)) {
            float ve = 0.f;
            #pragma unroll
            for (int mt = 0; mt < 4; ++mt)
                #pragma unroll
                for (int r = 0; r < 4; ++r)
                    ve = __builtin_fmaf(S[mt][r], ee[mt][r], ve);
            ve += __shfl_xor(ve, 16);
            ve += __shfl_xor(ve, 32);
            float cand = m + __logf(ve);
            lz = (len == t) ? cand : lz;
        }
    };

    // ---- staging offsets (swizzle verified element-wise; 2-way banks) ----
    uint32_t woff[4];
    #pragma unroll
    for (int pp = 0; pp < 4; ++pp) {
        const int chain = 4 * pp + (lane >> 4);
        uint32_t byte = ((uint32_t)chain << 8) + ((uint32_t)(lane & 15) << 4);
        byte ^= (uint32_t)((chain & 7) << 4);
        woff[pp] = byte;
    }
    uint32_t roff[4];
    #pragma unroll
    for (int mt = 0; mt < 4; ++mt) {
        uint32_t byte = ((uint32_t)c << 8) + ((uint32_t)mt << 6) + ((uint32_t)q << 4);
        byte ^= (uint32_t)((c & 7) << 4);
        roff[mt] = byte;
    }

    auto loadG = [&](int t, f32x4 (&G)[4]) {
        int tc = (t < TT) ? t : (TT - 1);
        const float* p = emit + ((size_t)tc << 16) + (size_t)b0 * NN + lane * 4;
        #pragma unroll
        for (int pp = 0; pp < 4; ++pp) {
            G[pp] = *(const f32x4*)(p + pp * 256);
            asm volatile("" : "+v"(G[pp]));   // block load sinking (keep distance)
        }
    };
    auto writeG = [&](int t, f32x4 (&G)[4]) {
        char* base = (char*)s_eb + (size_t)((t & 15) * 4096);
        #pragma unroll
        for (int pp = 0; pp < 4; ++pp)
            *(f32x4*)(base + woff[pp]) = G[pp];
    };
    auto ebRead = [&](int t, f32x4 (&E)[4]) {
        char* base = (char*)s_eb + (size_t)((t & 15) * 4096);
        #pragma unroll
        for (int mt = 0; mt < 4; ++mt)
            E[mt] = *(const f32x4*)(base + roff[mt]);
    };

    auto dostep = [&](int t, f32x4 (&Eraw)[4]) {
        extract_if(t);
        f32x4 EB[4];
        #pragma unroll
        for (int mt = 0; mt < 4; ++mt)
            #pragma unroll
            for (int r = 0; r < 4; ++r)
                EB[mt][r] = __expf(Eraw[mt][r]);
        uint32_t pk[4][2];
        #pragma unroll
        for (int mt = 0; mt < 4; ++mt) {
            pk[mt][0] = cvt_pk_bf16(S[mt][0], S[mt][1]);
            pk[mt][1] = cvt_pk_bf16(S[mt][2], S[mt][3]);
        }
        W8 B0, B1;
        {
            uint32_t a, bb;
            a = pk[0][0]; bb = pk[1][0]; perm32swap(a, bb); perm16swap(a, bb);
            B0.w[0] = a; B0.w[2] = bb;
            a = pk[0][1]; bb = pk[1][1]; perm32swap(a, bb); perm16swap(a, bb);
            B0.w[1] = a; B0.w[3] = bb;
            a = pk[2][0]; bb = pk[3][0]; perm32swap(a, bb); perm16swap(a, bb);
            B1.w[0] = a; B1.w[2] = bb;
            a = pk[2][1]; bb = pk[3][1]; perm32swap(a, bb); perm16swap(a, bb);
            B1.w[1] = a; B1.w[3] = bb;
        }
        #pragma unroll
        for (int mt = 0; mt < 4; ++mt) {
            f32x4 acc = {0.f, 0.f, 0.f, 0.f};
            acc = __builtin_amdgcn_mfma_f32_16x16x32_bf16(Ef[mt][0], B0.v, acc, 0, 0, 0);
            acc = __builtin_amdgcn_mfma_f32_16x16x32_bf16(Ef[mt][1], B1.v, acc, 0, 0, 0);
            #pragma unroll
            for (int r = 0; r < 4; ++r)
                S[mt][r] = acc[r] * EB[mt][r];
        }
        if ((t & 3) == 0) renorm();        // same cadence as R4/R7 (bit-identical)
    };

    if (NSTEP > 0) {
        f32x4 GA[4], GB[4], GC[4], EBa[4], EBb[4];
        // prologue: stage slots 1..9, then preload t=10..12 into regs
        loadG(1, GA); loadG(2, GB); loadG(3, GC);
        writeG(1, GA); writeG(2, GB); writeG(3, GC);
        loadG(4, GA); loadG(5, GB); loadG(6, GC);
        writeG(4, GA); writeG(5, GB); writeG(6, GC);
        loadG(7, GA); loadG(8, GB); loadG(9, GC);
        writeG(7, GA); writeG(8, GB); writeG(9, GC);
        loadG(10, GA); loadG(11, GB); loadG(12, GC);
        ebRead(1, EBa);

        int t = 1;
        while (t + 5 <= NSTEP) {   // 6 sub-steps: bufs A,B,C,A,B,C; EB ping-pong
            writeG(t + 9,  GA); loadG(t + 12, GA); ebRead(t + 1, EBb); dostep(t,     EBa);
            writeG(t + 10, GB); loadG(t + 13, GB); ebRead(t + 2, EBa); dostep(t + 1, EBb);
            writeG(t + 11, GC); loadG(t + 14, GC); ebRead(t + 3, EBb); dostep(t + 2, EBa);
            writeG(t + 12, GA); loadG(t + 15, GA); ebRead(t + 4, EBa); dostep(t + 3, EBb);
            writeG(t + 13, GB); loadG(t + 16, GB); ebRead(t + 5, EBb); dostep(t + 4, EBa);
            writeG(t + 14, GC); loadG(t + 17, GC); ebRead(t + 6, EBa); dostep(t + 5, EBb);
            t += 6;
        }
        // tail (≤5 steps): all needed slots already written; EBa holds slot t
        while (t <= NSTEP) {
            dostep(t, EBa);
            ++t;
            if (t <= NSTEP) ebRead(t, EBa);
        }
    }
    extract_if(maxlen);                     // chains with len == maxlen

    float contrib = (q == 0) ? lz : 0.f;
    #pragma unroll
    for (int off = 1; off < 64; off <<= 1) contrib += __shfl_xor(contrib, off);
    if (lane == 0) atomicAdd(out, contrib * (1.0f / (float)BB));
}

extern "C" void kernel_launch(void* const* d_in, const int* in_sizes, int n_in,
                              void* d_out, int out_size, void* d_ws, size_t ws_size,
                              hipStream_t stream) {
    const float* emit   = (const float*)d_in[0];
    const float* trans  = (const float*)d_in[1];
    const float* strans = (const float*)d_in[2];
    const float* etrans = (const float*)d_in[3];
    const void*  target = d_in[4];
    const void*  mask   = d_in[5];
    int* flags = (int*)d_ws;

    hipMemsetAsync(d_out, 0, sizeof(float), stream);
    detect_kernel<<<1, 64, 0, stream>>>((const uint32_t*)target,
                                        (const uint8_t*)mask, flags);
    score_kernel<<<(TT * BB) / 256, 256, 0, stream>>>(emit, trans, strans, etrans,
                                                      target, mask, flags, (float*)d_out);
    crf_scan<<<BB / 16, 64, 0, stream>>>(emit, trans, strans, etrans,
                                         mask, flags, (float*)d_out);
}

// Round 9
// 272.901 us; speedup vs baseline: 2.5314x; 2.5314x over previous
//
#include <hip/hip_runtime.h>
#include <stdint.h>

#define TT 512
#define BB 1024
#define NN 64

typedef __attribute__((ext_vector_type(8))) short short8;
typedef __attribute__((ext_vector_type(4))) float f32x4;

union W8 { uint32_t w[4]; short8 v; };

__device__ __forceinline__ uint32_t cvt_pk_bf16(float lo, float hi){
    uint32_t r;
    asm("v_cvt_pk_bf16_f32 %0, %1, %2" : "=v"(r) : "v"(lo), "v"(hi));
    return r;
}
// gfx950 cross-lane 16/32-group swaps (VALU, no LDS) — HW-validated R4.
__device__ __forceinline__ void perm32swap(uint32_t &a, uint32_t &b){
    asm("v_permlane32_swap_b32 %0, %1" : "+v"(a), "+v"(b));
}
__device__ __forceinline__ void perm16swap(uint32_t &a, uint32_t &b){
    asm("v_permlane16_swap_b32 %0, %1" : "+v"(a), "+v"(b));
}

// Detect input integer widths (harness may canonicalize int64->int32, bool->int32).
__global__ void __launch_bounds__(64, 1)
detect_kernel(const uint32_t* __restrict__ tgt, const uint8_t* __restrict__ msk,
              int* __restrict__ flags) {
    if (threadIdx.x == 0) {
        uint32_t s = 0;
        for (int i = 0; i < 128; ++i) s |= tgt[2 * i + 1];
        flags[0] = (s == 0) ? 1 : 0;   // 1 => target is int64
        uint32_t mz = 0;
        for (int i = 0; i < 8; ++i) mz |= msk[4*i+1] | msk[4*i+2] | msk[4*i+3];
        flags[1] = (mz == 0) ? 1 : 0;  // 1 => mask is int32
    }
}

// Gold-path score: fully parallel over (t, b). (Unchanged — passed R1-R8.)
__global__ void __launch_bounds__(256)
score_kernel(const float* __restrict__ emit, const float* __restrict__ trans,
             const float* __restrict__ strans, const float* __restrict__ etrans,
             const void* __restrict__ target, const void* __restrict__ mask,
             const int* __restrict__ flags, float* __restrict__ out)
{
    const int idx = blockIdx.x * 256 + threadIdx.x;   // T*B threads
    const int t = idx >> 10, b = idx & (BB - 1);
    const int t64 = flags[0], m32 = flags[1];

    auto getm = [&](int tt) -> int {
        if (m32) return ((const int*)mask)[(size_t)tt * BB + b] != 0;
        else     return ((const uint8_t*)mask)[(size_t)tt * BB + b] != 0;
    };
    auto gett = [&](int tt) -> int {
        if (t64) return (int)((const long long*)target)[(size_t)tt * BB + b];
        else     return ((const int*)target)[(size_t)tt * BB + b];
    };

    const int m  = getm(t);
    const int tg = gett(t);
    float term = 0.f;
    if (m)      term += emit[((size_t)t * BB + b) * NN + tg];
    if (t == 0) term += strans[tg];
    if (t > 0 && m) term += trans[gett(t - 1) * NN + tg];
    const int mn = (t == TT - 1) ? 0 : getm(t + 1);
    if (m && !mn) term += etrans[tg];   // t == len-1 (contiguous prefix)

    #pragma unroll
    for (int off = 1; off < 64; off <<= 1) term += __shfl_xor(term, off);
    __shared__ float sred[4];
    const int wid = threadIdx.x >> 6, lane = threadIdx.x & 63;
    if (lane == 0) sred[wid] = term;
    __syncthreads();
    if (threadIdx.x == 0)
        atomicAdd(out, -(sred[0] + sred[1] + sred[2] + sred[3]) * (1.0f / (float)BB));
}

// Forward scan, single wave per 16 chains (R4/R7-verified math) + SAME-WAVE
// LDS staging ring: 16 slots x 4KB. load(t+12) -> 3-substep reg hold ->
// ds_write(t+9, swizzled) -> ds_read(t+1) prefetch -> compute(t).
// Natural dep order enforces the pipeline: ds_write waits (counted vmcnt) on
// loads issued ~1000cyc earlier; WAR keeps reloads behind writes. NO value
// pins after loads (R8 lesson: "+v" pin forces synchronous load completion).
__global__ void __launch_bounds__(64, 1)
crf_scan(const float* __restrict__ emit, const float* __restrict__ trans,
         const float* __restrict__ strans, const float* __restrict__ etrans,
         const void* __restrict__ mask, const int* __restrict__ flags,
         float* __restrict__ out)
{
    __shared__ float s_eb[16 * 1024];   // 64 KB ring

    const int lane = threadIdx.x & 63;
    const int q = lane >> 4;
    const int c = lane & 15;
    const int b0 = blockIdx.x << 4;
    const int b = b0 + c;
    const int m32 = flags[1];

    // ---- per-chain length (contiguous-prefix mask), q-lanes split T ----
    int lp = 0;
    if (m32) {
        const int* mp = (const int*)mask;
        #pragma unroll 8
        for (int i = 0; i < 128; ++i)
            lp += (mp[(size_t)(q * 128 + i) * BB + b] != 0) ? 1 : 0;
    } else {
        const uint8_t* mp = (const uint8_t*)mask;
        #pragma unroll 8
        for (int i = 0; i < 128; ++i)
            lp += (mp[(size_t)(q * 128 + i) * BB + b] != 0) ? 1 : 0;
    }
    lp += __shfl_xor(lp, 16);
    lp += __shfl_xor(lp, 32);
    const int len = lp;
    int maxlen = len;
    #pragma unroll
    for (int off = 1; off < 64; off <<= 1)
        maxlen = max(maxlen, __shfl_xor(maxlen, off));
    const int NSTEP = maxlen - 1;

    // ---- A-operand: E^T tiles, E[j][n]=exp(trans[j][n]) (HW-verified R3/R4) ----
    short8 Ef[4][2];
    #pragma unroll
    for (int mt = 0; mt < 4; ++mt) {
        #pragma unroll
        for (int kt = 0; kt < 2; ++kt) {
            W8 u;
            #pragma unroll
            for (int jj = 0; jj < 8; jj += 2) {
                float f0 = __expf(trans[(size_t)(32*kt + 8*q + jj    ) * NN + 16*mt + c]);
                float f1 = __expf(trans[(size_t)(32*kt + 8*q + jj + 1) * NN + 16*mt + c]);
                u.w[jj >> 1] = cvt_pk_bf16(f0, f1);
            }
            Ef[mt][kt] = u.v;
        }
    }
    float ee[4][4];
    #pragma unroll
    for (int mt = 0; mt < 4; ++mt)
        #pragma unroll
        for (int r = 0; r < 4; ++r)
            ee[mt][r] = __expf(etrans[16*mt + 4*q + r]);

    // ---- state init: S = exp(strans + emit[0]) ----
    f32x4 S[4];
    float m = 0.f, lz = 0.f;
    #pragma unroll
    for (int mt = 0; mt < 4; ++mt) {
        f32x4 e0 = *(const f32x4*)(emit + (size_t)b * NN + 16*mt + 4*q);
        #pragma unroll
        for (int r = 0; r < 4; ++r)
            S[mt][r] = __expf(strans[16*mt + 4*q + r] + e0[r]);
    }

    auto renorm = [&]() {   // exact per-chain power-of-2 rescale
        float x0 = fmaxf(fmaxf(S[0][0], S[0][1]), fmaxf(S[0][2], S[0][3]));
        float x1 = fmaxf(fmaxf(S[1][0], S[1][1]), fmaxf(S[1][2], S[1][3]));
        float x2 = fmaxf(fmaxf(S[2][0], S[2][1]), fmaxf(S[2][2], S[2][3]));
        float x3 = fmaxf(fmaxf(S[3][0], S[3][1]), fmaxf(S[3][2], S[3][3]));
        float mx = fmaxf(fmaxf(x0, x1), fmaxf(x2, x3));
        mx = fmaxf(mx, __shfl_xor(mx, 16));
        mx = fmaxf(mx, __shfl_xor(mx, 32));
        int ex = (int)((__float_as_uint(mx) >> 23) & 0xffu) - 127;
        float sc = __uint_as_float((uint32_t)(127 - ex) << 23);   // exact 2^-ex
        #pragma unroll
        for (int mt = 0; mt < 4; ++mt)
            #pragma unroll
            for (int r = 0; r < 4; ++r)
                S[mt][r] *= sc;
        m += (float)ex * 0.6931471805599453f;
    };
    renorm();

    auto extract_if = [&](int t) {   // latch logZ for chains with len == t
        if (__any(len == t)) {
            float ve = 0.f;
            #pragma unroll
            for (int mt = 0; mt < 4; ++mt)
                #pragma unroll
                for (int r = 0; r < 4; ++r)
                    ve = __builtin_fmaf(S[mt][r], ee[mt][r], ve);
            ve += __shfl_xor(ve, 16);
            ve += __shfl_xor(ve, 32);
            float cand = m + __logf(ve);
            lz = (len == t) ? cand : lz;
        }
    };

    // ---- staging offsets (swizzle verified element-wise; modest conflicts) ----
    uint32_t woff[4];
    #pragma unroll
    for (int pp = 0; pp < 4; ++pp) {
        const int chain = 4 * pp + (lane >> 4);
        uint32_t byte = ((uint32_t)chain << 8) + ((uint32_t)(lane & 15) << 4);
        byte ^= (uint32_t)((chain & 7) << 4);
        woff[pp] = byte;
    }
    uint32_t roff[4];
    #pragma unroll
    for (int mt = 0; mt < 4; ++mt) {
        uint32_t byte = ((uint32_t)c << 8) + ((uint32_t)mt << 6) + ((uint32_t)q << 4);
        byte ^= (uint32_t)((c & 7) << 4);
        roff[mt] = byte;
    }

    auto loadG = [&](int t, f32x4 (&G)[4]) {
        int tc = (t < TT) ? t : (TT - 1);
        const float* p = emit + ((size_t)tc << 16) + (size_t)b0 * NN + lane * 4;
        #pragma unroll
        for (int pp = 0; pp < 4; ++pp)
            G[pp] = *(const f32x4*)(p + pp * 256);
    };
    auto writeG = [&](int t, f32x4 (&G)[4]) {
        char* base = (char*)s_eb + (size_t)((t & 15) * 4096);
        #pragma unroll
        for (int pp = 0; pp < 4; ++pp)
            *(f32x4*)(base + woff[pp]) = G[pp];
    };
    auto ebRead = [&](int t, f32x4 (&E)[4]) {
        char* base = (char*)s_eb + (size_t)((t & 15) * 4096);
        #pragma unroll
        for (int mt = 0; mt < 4; ++mt)
            E[mt] = *(const f32x4*)(base + roff[mt]);
    };

    auto dostep = [&](int t, f32x4 (&Eraw)[4]) {
        extract_if(t);
        f32x4 EB[4];
        #pragma unroll
        for (int mt = 0; mt < 4; ++mt)
            #pragma unroll
            for (int r = 0; r < 4; ++r)
                EB[mt][r] = __expf(Eraw[mt][r]);
        uint32_t pk[4][2];
        #pragma unroll
        for (int mt = 0; mt < 4; ++mt) {
            pk[mt][0] = cvt_pk_bf16(S[mt][0], S[mt][1]);
            pk[mt][1] = cvt_pk_bf16(S[mt][2], S[mt][3]);
        }
        W8 B0, B1;
        {
            uint32_t a, bb;
            a = pk[0][0]; bb = pk[1][0]; perm32swap(a, bb); perm16swap(a, bb);
            B0.w[0] = a; B0.w[2] = bb;
            a = pk[0][1]; bb = pk[1][1]; perm32swap(a, bb); perm16swap(a, bb);
            B0.w[1] = a; B0.w[3] = bb;
            a = pk[2][0]; bb = pk[3][0]; perm32swap(a, bb); perm16swap(a, bb);
            B1.w[0] = a; B1.w[2] = bb;
            a = pk[2][1]; bb = pk[3][1]; perm32swap(a, bb); perm16swap(a, bb);
            B1.w[1] = a; B1.w[3] = bb;
        }
        #pragma unroll
        for (int mt = 0; mt < 4; ++mt) {
            f32x4 acc = {0.f, 0.f, 0.f, 0.f};
            acc = __builtin_amdgcn_mfma_f32_16x16x32_bf16(Ef[mt][0], B0.v, acc, 0, 0, 0);
            acc = __builtin_amdgcn_mfma_f32_16x16x32_bf16(Ef[mt][1], B1.v, acc, 0, 0, 0);
            #pragma unroll
            for (int r = 0; r < 4; ++r)
                S[mt][r] = acc[r] * EB[mt][r];
        }
        if ((t & 3) == 0) renorm();        // same cadence as R4/R7 (bit-identical)
    };

    if (NSTEP > 0) {
        f32x4 GA[4], GB[4], GC[4], EBa[4], EBb[4];
        // prologue: stage slots 1..9, then preload t=10..12 into regs
        loadG(1, GA); loadG(2, GB); loadG(3, GC);
        writeG(1, GA); writeG(2, GB); writeG(3, GC);
        loadG(4, GA); loadG(5, GB); loadG(6, GC);
        writeG(4, GA); writeG(5, GB); writeG(6, GC);
        loadG(7, GA); loadG(8, GB); loadG(9, GC);
        writeG(7, GA); writeG(8, GB); writeG(9, GC);
        loadG(10, GA); loadG(11, GB); loadG(12, GC);
        ebRead(1, EBa);

        int t = 1;
        while (t + 5 <= NSTEP) {   // 6 sub-steps: bufs A,B,C,A,B,C; EB ping-pong
            writeG(t + 9,  GA); loadG(t + 12, GA); ebRead(t + 1, EBb); dostep(t,     EBa);
            writeG(t + 10, GB); loadG(t + 13, GB); ebRead(t + 2, EBa); dostep(t + 1, EBb);
            writeG(t + 11, GC); loadG(t + 14, GC); ebRead(t + 3, EBb); dostep(t + 2, EBa);
            writeG(t + 12, GA); loadG(t + 15, GA); ebRead(t + 4, EBa); dostep(t + 3, EBb);
            writeG(t + 13, GB); loadG(t + 16, GB); ebRead(t + 5, EBb); dostep(t + 4, EBa);
            writeG(t + 14, GC); loadG(t + 17, GC); ebRead(t + 6, EBa); dostep(t + 5, EBb);
            t += 6;
        }
        // tail (≤5 steps): all needed slots already written; EBa holds slot t
        while (t <= NSTEP) {
            dostep(t, EBa);
            ++t;
            if (t <= NSTEP) ebRead(t, EBa);
        }
    }
    extract_if(maxlen);                     // chains with len == maxlen

    float contrib = (q == 0) ? lz : 0.f;
    #pragma unroll
    for (int off = 1; off < 64; off <<= 1) contrib += __shfl_xor(contrib, off);
    if (lane == 0) atomicAdd(out, contrib * (1.0f / (float)BB));
}

extern "C" void kernel_launch(void* const* d_in, const int* in_sizes, int n_in,
                              void* d_out, int out_size, void* d_ws, size_t ws_size,
                              hipStream_t stream) {
    const float* emit   = (const float*)d_in[0];
    const float* trans  = (const float*)d_in[1];
    const float* strans = (const float*)d_in[2];
    const float* etrans = (const float*)d_in[3];
    const void*  target = d_in[4];
    const void*  mask   = d_in[5];
    int* flags = (int*)d_ws;

    hipMemsetAsync(d_out, 0, sizeof(float), stream);
    detect_kernel<<<1, 64, 0, stream>>>((const uint32_t*)target,
                                        (const uint8_t*)mask, flags);
    score_kernel<<<(TT * BB) / 256, 256, 0, stream>>>(emit, trans, strans, etrans,
                                                      target, mask, flags, (float*)d_out);
    crf_scan<<<BB / 16, 64, 0, stream>>>(emit, trans, strans, etrans,
                                         mask, flags, (float*)d_out);
}

// Round 10
// 209.200 us; speedup vs baseline: 3.3023x; 1.3045x over previous
//
#include <hip/hip_runtime.h>
#include <stdint.h>

#define TT 512
#define BB 1024
#define NN 64

typedef __attribute__((ext_vector_type(8))) short short8;
typedef __attribute__((ext_vector_type(4))) float f32x4;

union W8 { uint32_t w[4]; short8 v; };

__device__ __forceinline__ uint32_t cvt_pk_bf16(float lo, float hi){
    uint32_t r;
    asm("v_cvt_pk_bf16_f32 %0, %1, %2" : "=v"(r) : "v"(lo), "v"(hi));
    return r;
}
// gfx950 cross-lane 16/32-group swaps (VALU, no LDS) — HW-validated R4.
__device__ __forceinline__ void perm32swap(uint32_t &a, uint32_t &b){
    asm("v_permlane32_swap_b32 %0, %1" : "+v"(a), "+v"(b));
}
__device__ __forceinline__ void perm16swap(uint32_t &a, uint32_t &b){
    asm("v_permlane16_swap_b32 %0, %1" : "+v"(a), "+v"(b));
}
// Async staging loads: compiler sees outputs as defined, inserts NO waitcnt.
__device__ __forceinline__ void ld4o(const float* p, f32x4 &d0, f32x4 &d1,
                                     f32x4 &d2, f32x4 &d3){
    asm volatile("global_load_dwordx4 %0, %4, off\n\t"
                 "global_load_dwordx4 %1, %4, off offset:1024\n\t"
                 "global_load_dwordx4 %2, %4, off offset:2048\n\t"
                 "global_load_dwordx4 %3, %4, off offset:3072"
                 : "=&v"(d0), "=&v"(d1), "=&v"(d2), "=&v"(d3)
                 : "v"(p) : "memory");
}
// Counted wait that DEFINES the slot regs: consumers are data-dependent on it
// (unlike r282's hazard where the waited reg wasn't an asm operand).
__device__ __forceinline__ void waitv28(f32x4 &a, f32x4 &b, f32x4 &c, f32x4 &d){
    asm volatile("s_waitcnt vmcnt(28)" : "+v"(a), "+v"(b), "+v"(c), "+v"(d));
}

// Detect input integer widths (harness may canonicalize int64->int32, bool->int32).
__global__ void __launch_bounds__(64, 1)
detect_kernel(const uint32_t* __restrict__ tgt, const uint8_t* __restrict__ msk,
              int* __restrict__ flags) {
    if (threadIdx.x == 0) {
        uint32_t s = 0;
        for (int i = 0; i < 128; ++i) s |= tgt[2 * i + 1];
        flags[0] = (s == 0) ? 1 : 0;   // 1 => target is int64
        uint32_t mz = 0;
        for (int i = 0; i < 8; ++i) mz |= msk[4*i+1] | msk[4*i+2] | msk[4*i+3];
        flags[1] = (mz == 0) ? 1 : 0;  // 1 => mask is int32
    }
}

// Gold-path score: fully parallel over (t, b). (Unchanged — passed R1-R9.)
__global__ void __launch_bounds__(256)
score_kernel(const float* __restrict__ emit, const float* __restrict__ trans,
             const float* __restrict__ strans, const float* __restrict__ etrans,
             const void* __restrict__ target, const void* __restrict__ mask,
             const int* __restrict__ flags, float* __restrict__ out)
{
    const int idx = blockIdx.x * 256 + threadIdx.x;   // T*B threads
    const int t = idx >> 10, b = idx & (BB - 1);
    const int t64 = flags[0], m32 = flags[1];

    auto getm = [&](int tt) -> int {
        if (m32) return ((const int*)mask)[(size_t)tt * BB + b] != 0;
        else     return ((const uint8_t*)mask)[(size_t)tt * BB + b] != 0;
    };
    auto gett = [&](int tt) -> int {
        if (t64) return (int)((const long long*)target)[(size_t)tt * BB + b];
        else     return ((const int*)target)[(size_t)tt * BB + b];
    };

    const int m  = getm(t);
    const int tg = gett(t);
    float term = 0.f;
    if (m)      term += emit[((size_t)t * BB + b) * NN + tg];
    if (t == 0) term += strans[tg];
    if (t > 0 && m) term += trans[gett(t - 1) * NN + tg];
    const int mn = (t == TT - 1) ? 0 : getm(t + 1);
    if (m && !mn) term += etrans[tg];   // t == len-1 (contiguous prefix)

    #pragma unroll
    for (int off = 1; off < 64; off <<= 1) term += __shfl_xor(term, off);
    __shared__ float sred[4];
    const int wid = threadIdx.x >> 6, lane = threadIdx.x & 63;
    if (lane == 0) sred[wid] = term;
    __syncthreads();
    if (threadIdx.x == 0)
        atomicAdd(out, -(sred[0] + sred[1] + sred[2] + sred[3]) * (1.0f / (float)BB));
}

// Forward scan, single wave per 16 chains (R4/R7-verified math).
// Depth-8 REGISTER ring with inline-asm loads + counted vmcnt(28):
// invariant 32 loads in flight; slot k waited exactly 8 steps after issue
// (~2200 cyc distance >> ~900 cyc HBM). Loop padded to multiple of 8
// (freeze-free latch makes overrun harmless); no tail, single final drain.
__global__ void __launch_bounds__(64, 1)
crf_scan(const float* __restrict__ emit, const float* __restrict__ trans,
         const float* __restrict__ strans, const float* __restrict__ etrans,
         const void* __restrict__ mask, const int* __restrict__ flags,
         float* __restrict__ out)
{
    const int lane = threadIdx.x & 63;
    const int q = lane >> 4;
    const int c = lane & 15;
    const int b0 = blockIdx.x << 4;
    const int b = b0 + c;
    const int m32 = flags[1];

    // ---- per-chain length (contiguous-prefix mask), q-lanes split T ----
    int lp = 0;
    if (m32) {
        const int* mp = (const int*)mask;
        #pragma unroll 8
        for (int i = 0; i < 128; ++i)
            lp += (mp[(size_t)(q * 128 + i) * BB + b] != 0) ? 1 : 0;
    } else {
        const uint8_t* mp = (const uint8_t*)mask;
        #pragma unroll 8
        for (int i = 0; i < 128; ++i)
            lp += (mp[(size_t)(q * 128 + i) * BB + b] != 0) ? 1 : 0;
    }
    lp += __shfl_xor(lp, 16);
    lp += __shfl_xor(lp, 32);
    const int len = lp;
    int maxlen = len;
    #pragma unroll
    for (int off = 1; off < 64; off <<= 1)
        maxlen = max(maxlen, __shfl_xor(maxlen, off));
    const int NPAD = (maxlen + 7) & ~7;     // padded step count (multiple of 8)

    // ---- A-operand: E^T tiles, E[j][n]=exp(trans[j][n]) (HW-verified R3/R4) ----
    short8 Ef[4][2];
    #pragma unroll
    for (int mt = 0; mt < 4; ++mt) {
        #pragma unroll
        for (int kt = 0; kt < 2; ++kt) {
            W8 u;
            #pragma unroll
            for (int jj = 0; jj < 8; jj += 2) {
                float f0 = __expf(trans[(size_t)(32*kt + 8*q + jj    ) * NN + 16*mt + c]);
                float f1 = __expf(trans[(size_t)(32*kt + 8*q + jj + 1) * NN + 16*mt + c]);
                u.w[jj >> 1] = cvt_pk_bf16(f0, f1);
            }
            Ef[mt][kt] = u.v;
        }
    }
    float ee[4][4];
    #pragma unroll
    for (int mt = 0; mt < 4; ++mt)
        #pragma unroll
        for (int r = 0; r < 4; ++r)
            ee[mt][r] = __expf(etrans[16*mt + 4*q + r]);

    // ---- state init: S = exp(strans + emit[0]) ----
    f32x4 S[4];
    float m = 0.f, lz = 0.f;
    #pragma unroll
    for (int mt = 0; mt < 4; ++mt) {
        f32x4 e0 = *(const f32x4*)(emit + (size_t)b * NN + 16*mt + 4*q);
        #pragma unroll
        for (int r = 0; r < 4; ++r)
            S[mt][r] = __expf(strans[16*mt + 4*q + r] + e0[r]);
    }

    auto renorm = [&]() {   // exact per-chain power-of-2 rescale
        float x0 = fmaxf(fmaxf(S[0][0], S[0][1]), fmaxf(S[0][2], S[0][3]));
        float x1 = fmaxf(fmaxf(S[1][0], S[1][1]), fmaxf(S[1][2], S[1][3]));
        float x2 = fmaxf(fmaxf(S[2][0], S[2][1]), fmaxf(S[2][2], S[2][3]));
        float x3 = fmaxf(fmaxf(S[3][0], S[3][1]), fmaxf(S[3][2], S[3][3]));
        float mx = fmaxf(fmaxf(x0, x1), fmaxf(x2, x3));
        mx = fmaxf(mx, __shfl_xor(mx, 16));
        mx = fmaxf(mx, __shfl_xor(mx, 32));
        int ex = (int)((__float_as_uint(mx) >> 23) & 0xffu) - 127;
        float sc = __uint_as_float((uint32_t)(127 - ex) << 23);   // exact 2^-ex
        #pragma unroll
        for (int mt = 0; mt < 4; ++mt)
            #pragma unroll
            for (int r = 0; r < 4; ++r)
                S[mt][r] *= sc;
        m += (float)ex * 0.6931471805599453f;
    };
    renorm();

    auto extract_if = [&](int t) {   // latch logZ for chains with len == t
        if (__any(len == t)) {
            float ve = 0.f;
            #pragma unroll
            for (int mt = 0; mt < 4; ++mt)
                #pragma unroll
                for (int r = 0; r < 4; ++r)
                    ve = __builtin_fmaf(S[mt][r], ee[mt][r], ve);
            ve += __shfl_xor(ve, 16);
            ve += __shfl_xor(ve, 32);
            float cand = m + __logf(ve);
            lz = (len == t) ? cand : lz;
        }
    };

    // ---- async staging: issue 4 dwordx4 for step t into slot regs ----
    auto issueG = [&](int t, f32x4 (&G)[4]) {
        int tc = (t < TT) ? t : (TT - 1);
        const float* p = emit + ((size_t)tc << 16) + (size_t)b0 * NN + lane * 4;
        ld4o(p, G[0], G[1], G[2], G[3]);
    };

    auto dostep = [&](int t, f32x4 (&Eraw)[4]) {
        extract_if(t);
        f32x4 EB[4];
        #pragma unroll
        for (int mt = 0; mt < 4; ++mt)
            #pragma unroll
            for (int r = 0; r < 4; ++r)
                EB[mt][r] = __expf(Eraw[mt][r]);
        uint32_t pk[4][2];
        #pragma unroll
        for (int mt = 0; mt < 4; ++mt) {
            pk[mt][0] = cvt_pk_bf16(S[mt][0], S[mt][1]);
            pk[mt][1] = cvt_pk_bf16(S[mt][2], S[mt][3]);
        }
        W8 B0, B1;
        {
            uint32_t a, bb;
            a = pk[0][0]; bb = pk[1][0]; perm32swap(a, bb); perm16swap(a, bb);
            B0.w[0] = a; B0.w[2] = bb;
            a = pk[0][1]; bb = pk[1][1]; perm32swap(a, bb); perm16swap(a, bb);
            B0.w[1] = a; B0.w[3] = bb;
            a = pk[2][0]; bb = pk[3][0]; perm32swap(a, bb); perm16swap(a, bb);
            B1.w[0] = a; B1.w[2] = bb;
            a = pk[2][1]; bb = pk[3][1]; perm32swap(a, bb); perm16swap(a, bb);
            B1.w[1] = a; B1.w[3] = bb;
        }
        #pragma unroll
        for (int mt = 0; mt < 4; ++mt) {
            f32x4 acc = {0.f, 0.f, 0.f, 0.f};
            acc = __builtin_amdgcn_mfma_f32_16x16x32_bf16(Ef[mt][0], B0.v, acc, 0, 0, 0);
            acc = __builtin_amdgcn_mfma_f32_16x16x32_bf16(Ef[mt][1], B1.v, acc, 0, 0, 0);
            #pragma unroll
            for (int r = 0; r < 4; ++r)
                S[mt][r] = acc[r] * EB[mt][r];
        }
        if ((t & 3) == 0) renorm();        // same cadence as R4/R7 (bit-identical)
    };

    // ---- main loop: padded, uniform, no tail ----
    f32x4 R[8][4];
    #pragma unroll
    for (int k = 0; k < 8; ++k) issueG(1 + k, R[k]);   // 32 loads in flight

    for (int t = 1; t <= NPAD; t += 8) {
        #pragma unroll
        for (int k = 0; k < 8; ++k) {
            waitv28(R[k][0], R[k][1], R[k][2], R[k][3]);  // slot k landed
            dostep(t + k, R[k]);
            issueG(t + k + 8, R[k]);                      // refill -> 32 in flight
        }
    }
    // drain; tie to lz so the epilogue is ordered after landing loads
    asm volatile("s_waitcnt vmcnt(0)" : "+v"(lz));

    float contrib = (q == 0) ? lz : 0.f;
    #pragma unroll
    for (int off = 1; off < 64; off <<= 1) contrib += __shfl_xor(contrib, off);
    if (lane == 0) atomicAdd(out, contrib * (1.0f / (float)BB));
}

extern "C" void kernel_launch(void* const* d_in, const int* in_sizes, int n_in,
                              void* d_out, int out_size, void* d_ws, size_t ws_size,
                              hipStream_t stream) {
    const float* emit   = (const float*)d_in[0];
    const float* trans  = (const float*)d_in[1];
    const float* strans = (const float*)d_in[2];
    const float* etrans = (const float*)d_in[3];
    const void*  target = d_in[4];
    const void*  mask   = d_in[5];
    int* flags = (int*)d_ws;

    hipMemsetAsync(d_out, 0, sizeof(float), stream);
    detect_kernel<<<1, 64, 0, stream>>>((const uint32_t*)target,
                                        (const uint8_t*)mask, flags);
    score_kernel<<<(TT * BB) / 256, 256, 0, stream>>>(emit, trans, strans, etrans,
                                                      target, mask, flags, (float*)d_out);
    crf_scan<<<BB / 16, 64, 0, stream>>>(emit, trans, strans, etrans,
                                         mask, flags, (float*)d_out);
}